// Round 3
// baseline (22816.261 us; speedup 1.0000x reference)
//
#include <hip/hip_runtime.h>
#include <math.h>

typedef _Float16 h8 __attribute__((ext_vector_type(8)));
typedef float f4 __attribute__((ext_vector_type(4)));

#define H 1024

// ---- workspace layout (bytes) ----
#define OFF_WRZ0 0ull
#define OFF_WN0  6291456ull
#define OFF_WRZ1 9437184ull
#define OFF_WN1  17825792ull
#define OFF_H0BF 22020096ull   // _Float16 [2][64][1024] master
#define OFF_H1BF 22282240ull   // _Float16 [2][64][1024] master
#define OFF_RH0  22544384ull   // _Float16 [64][1024] master
#define OFF_RH1  22675456ull   // _Float16 [64][1024] master
#define OFF_H0F  22806528ull   // float [64][1024] master
#define OFF_H1F  23068672ull   // float [64][1024] master
#define OFF_Z0F  23330816ull   // float [64][1024] master
#define OFF_Z1F  23592960ull   // float [64][1024] master
#define OFF_CNT  23855104ull   // u64[8]: [0..3] phase flags, [4] init
#define OFF_INFO 23855168ull   // u32[128] block->xcd
#define OFF_CCNT 23855680ull   // u64[8][4] per-xcd copy counters
#define OFF_CP   23859200ull   // per-xcd copies [8][4 tensors][2 par][131072 B]
#define CP_XCD_STRIDE 1048576ull
#define ZERO_WORDS 458960      // (23855936 - 22020096)/4

// ---------------- LLC-bypass (agent-scope relaxed) helpers ----------------
__device__ __forceinline__ unsigned long long llc_ld64(const void* p) {
  return __hip_atomic_load((const unsigned long long*)p, __ATOMIC_RELAXED, __HIP_MEMORY_SCOPE_AGENT);
}
__device__ __forceinline__ void llc_st64(void* p, unsigned long long v) {
  __hip_atomic_store((unsigned long long*)p, v, __ATOMIC_RELAXED, __HIP_MEMORY_SCOPE_AGENT);
}
__device__ __forceinline__ void llc_st32(void* p, unsigned v) {
  __hip_atomic_store((unsigned*)p, v, __ATOMIC_RELAXED, __HIP_MEMORY_SCOPE_AGENT);
}
__device__ __forceinline__ unsigned long long pack2f(float a, float b) {
  union { float f[2]; unsigned long long u; } x; x.f[0] = a; x.f[1] = b; return x.u;
}
__device__ __forceinline__ void unpack2f(unsigned long long v, float& a, float& b) {
  union { unsigned long long u; float f[2]; } x; x.u = v; a = x.f[0]; b = x.f[1];
}
__device__ __forceinline__ unsigned packh2(float a, float b) {
  union { _Float16 h[2]; unsigned u; } x; x.h[0] = (_Float16)a; x.h[1] = (_Float16)b; return x.u;
}

// ---------------- prep: weights fp32->fp16, zero comm region ----------------
__global__ __launch_bounds__(256) void prep_kernel(
    const float* __restrict__ wrz0f, const float* __restrict__ wn0f,
    const float* __restrict__ wrz1f, const float* __restrict__ wn1f,
    _Float16* __restrict__ wrz0, _Float16* __restrict__ wn0,
    _Float16* __restrict__ wrz1, _Float16* __restrict__ wn1,
    unsigned* __restrict__ zbase) {
  size_t i = (size_t)blockIdx.x * blockDim.x + threadIdx.x;
  size_t stride = (size_t)gridDim.x * blockDim.x;
  for (size_t k = i; k < 2048ull * 1536ull; k += stride) wrz0[k] = (_Float16)wrz0f[k];
  for (size_t k = i; k < 1024ull * 1536ull; k += stride) wn0[k]  = (_Float16)wn0f[k];
  for (size_t k = i; k < 2048ull * 2048ull; k += stride) wrz1[k] = (_Float16)wrz1f[k];
  for (size_t k = i; k < 1024ull * 2048ull; k += stride) wn1[k]  = (_Float16)wn1f[k];
  for (size_t k = i; k < (size_t)ZERO_WORDS; k += stride) zbase[k] = 0u;
}

// ---------------- flag wait/signal (no cache maintenance) ----------------
__device__ __forceinline__ void wait_ge(unsigned long long* c, unsigned long long tgt) {
  if (threadIdx.x == 0) {
    while (__hip_atomic_load(c, __ATOMIC_RELAXED, __HIP_MEMORY_SCOPE_AGENT) < tgt)
      __builtin_amdgcn_s_sleep(2);
  }
  __syncthreads();
}
// __syncthreads drains vmcnt(0) before s_barrier -> all LLC stores visible
// before thread 0 increments the flag.
__device__ __forceinline__ void signal(unsigned long long* c) {
  __syncthreads();
  if (threadIdx.x == 0)
    __hip_atomic_fetch_add(c, 1ull, __ATOMIC_RELAXED, __HIP_MEMORY_SCOPE_AGENT);
}

// ---------------- cooperative per-XCD copy: master(LLC) -> xcd copy(L2) ----------------
// m same-XCD blocks each copy a strided slice (u64 granules), count arrivals in
// an LLC counter, wait target, then buffer_inv sc0 (L1-only invalidate) so
// subsequent NORMAL loads of the copy are served fresh from this XCD's L2.
__device__ __forceinline__ void copy_tensor(const void* __restrict__ master,
                                            void* __restrict__ cp,
                                            int rank, int m,
                                            unsigned long long* ccnt,
                                            unsigned long long target) {
  const unsigned long long* src = (const unsigned long long*)master;
  unsigned long long* dst = (unsigned long long*)cp;
  for (int u = rank * 1024 + (int)threadIdx.x; u < 16384; u += m * 1024)
    dst[u] = llc_ld64(src + u);
  __syncthreads();   // drain vmcnt for all waves (stores at L2)
  if (threadIdx.x == 0) {
    __hip_atomic_fetch_add(ccnt, 1ull, __ATOMIC_RELAXED, __HIP_MEMORY_SCOPE_AGENT);
    while (__hip_atomic_load(ccnt, __ATOMIC_RELAXED, __HIP_MEMORY_SCOPE_AGENT) < target)
      __builtin_amdgcn_s_sleep(2);
  }
  __syncthreads();
  asm volatile("buffer_inv sc0" ::: "memory");  // invalidate this CU's L1 only
}

// ---------------- GEMM over an L2-resident copy [64][1024] fp16 ----------------
// 16 waves = 4 mw (row groups of 16) x 4 kwq (K quarters of 256).
template<int NT>
__device__ __forceinline__ void gemm_cp(const _Float16* __restrict__ A,
                                        const _Float16* const* wps, int coff, f4* acc) {
  const int lane = threadIdx.x & 63, wv = threadIdx.x >> 6;
  const int kwq = wv & 3, mw = wv >> 2;
  const int rsub = lane & 15, kg = (lane >> 4) << 3;
  const _Float16* ap = A + (size_t)(mw * 16 + rsub) * 1024 + kwq * 256 + kg;
#pragma unroll
  for (int k0 = 0; k0 < 256; k0 += 32) {
    h8 a = *(const h8*)(ap + k0);
    int kc = coff + kwq * 256 + k0 + kg;
#pragma unroll
    for (int c = 0; c < NT; ++c) {
      h8 wf = *(const h8*)(wps[c] + kc);
      acc[c] = __builtin_amdgcn_mfma_f32_16x16x32_f16(a, wf, acc[c], 0, 0, 0);
    }
  }
}

// x-part GEMM (layer0, K=512, fp32 x converted in-register); rz(2 tiles) + n(1 tile)
__device__ __forceinline__ void gemm_x(const float* __restrict__ x, int t,
                                       const _Float16* __restrict__ wr0,
                                       const _Float16* __restrict__ wr1,
                                       const _Float16* __restrict__ wn,
                                       f4* aRZ, f4* aN) {
  const int lane = threadIdx.x & 63, wv = threadIdx.x >> 6;
  const int kwq = wv & 3, mw = wv >> 2;
  const int rsub = lane & 15, kg = (lane >> 4) << 3;
  const float* xb = x + (size_t)(mw * 16 + rsub) * 262144 + (size_t)t * 512;
#pragma unroll
  for (int k0 = 0; k0 < 128; k0 += 32) {
    int k = kwq * 128 + k0 + kg;
    float4 f0 = *(const float4*)(xb + k);
    float4 f1 = *(const float4*)(xb + k + 4);
    h8 a;
    a[0] = (_Float16)f0.x; a[1] = (_Float16)f0.y; a[2] = (_Float16)f0.z; a[3] = (_Float16)f0.w;
    a[4] = (_Float16)f1.x; a[5] = (_Float16)f1.y; a[6] = (_Float16)f1.z; a[7] = (_Float16)f1.w;
    aRZ[0] = __builtin_amdgcn_mfma_f32_16x16x32_f16(a, *(const h8*)(wr0 + k), aRZ[0], 0, 0, 0);
    aRZ[1] = __builtin_amdgcn_mfma_f32_16x16x32_f16(a, *(const h8*)(wr1 + k), aRZ[1], 0, 0, 0);
    aN[0]  = __builtin_amdgcn_mfma_f32_16x16x32_f16(a, *(const h8*)(wn + k),  aN[0], 0, 0, 0);
  }
}

// per-wave partials -> LDS red[kwq][64 rows][<=32 cols], stride 33
template<int NT>
__device__ __forceinline__ void red_write(float* __restrict__ red, const f4* acc) {
  const int lane = threadIdx.x & 63, wv = threadIdx.x >> 6;
  const int kwq = wv & 3, mw = wv >> 2;
  const int rsub = lane & 15, rg = lane >> 4;
#pragma unroll
  for (int c = 0; c < NT; ++c)
#pragma unroll
    for (int j = 0; j < 4; ++j)
      red[(size_t)(kwq * 64 + mw * 16 + rg * 4 + j) * 33 + c * 16 + rsub] = acc[c][j];
}

// rz reduce+apply: sigmoid; r-cols write rh=r*h (fp16), z-cols write z (f32)
__device__ __forceinline__ void reduce_rz(const float* __restrict__ red, int cb,
    const float* __restrict__ bias, const float* __restrict__ hf,
    _Float16* __restrict__ rh, float* __restrict__ zf) {
  const int tid = threadIdx.x;
  const int row = tid >> 4, cp = (tid & 15) << 1;
  float v0 = 0.f, v1 = 0.f;
#pragma unroll
  for (int q = 0; q < 4; ++q) {
    const float* rr = red + (size_t)(q * 64 + row) * 33 + cp;
    v0 += rr[0]; v1 += rr[1];
  }
  v0 += bias[cb + cp]; v1 += bias[cb + cp + 1];
  float s0 = 1.f / (1.f + expf(-v0));
  float s1 = 1.f / (1.f + expf(-v1));
  if (cb < 1024) {
    float h0v, h1v;
    unpack2f(llc_ld64(hf + (size_t)row * H + cb + cp), h0v, h1v);
    llc_st32(rh + (size_t)row * H + cb + cp, packh2(s0 * h0v, s1 * h1v));
  } else {
    llc_st64(zf + (size_t)row * H + (cb - 1024) + cp, pack2f(s0, s1));
  }
}

// n reduce+apply + h update (f32 master + fp16 master)
__device__ __forceinline__ void reduce_n(const float* __restrict__ red, int nb,
    const float* __restrict__ bias, const float* __restrict__ zf,
    float* __restrict__ hf, _Float16* __restrict__ hb) {
  const int tid = threadIdx.x;
  if (tid < 512) {
    const int row = tid >> 3, cp = (tid & 7) << 1;
    float v0 = 0.f, v1 = 0.f;
#pragma unroll
    for (int q = 0; q < 4; ++q) {
      const float* rr = red + (size_t)(q * 64 + row) * 33 + cp;
      v0 += rr[0]; v1 += rr[1];
    }
    v0 += bias[nb + cp]; v1 += bias[nb + cp + 1];
    float n0 = tanhf(v0), n1 = tanhf(v1);
    float z0, z1, h0v, h1v;
    unpack2f(llc_ld64(zf + (size_t)row * H + nb + cp), z0, z1);
    unpack2f(llc_ld64(hf + (size_t)row * H + nb + cp), h0v, h1v);
    float o0 = (1.f - z0) * n0 + z0 * h0v;
    float o1 = (1.f - z1) * n1 + z1 * h1v;
    llc_st64(hf + (size_t)row * H + nb + cp, pack2f(o0, o1));
    llc_st32(hb + (size_t)row * H + nb + cp, packh2(o0, o1));
  }
}

// ---------------- persistent GRU kernel ----------------
// cnt[0]=c_rz0, cnt[1]=c_n0, cnt[2]=c_rz1, cnt[3]=c_n1, cnt[4]=init counter.
// ccnt[xcd][tau]: tau 0=H0, 1=RH0, 2=H1, 3=RH1.
__global__ __launch_bounds__(1024) void gru_main(const float* __restrict__ x,
    const _Float16* __restrict__ wrz0, const _Float16* __restrict__ wn0,
    const _Float16* __restrict__ wrz1, const _Float16* __restrict__ wn1,
    const float* __restrict__ brz0, const float* __restrict__ bn0,
    const float* __restrict__ brz1, const float* __restrict__ bn1,
    _Float16* __restrict__ h0bf, _Float16* __restrict__ h1bf,
    _Float16* __restrict__ rh0, _Float16* __restrict__ rh1,
    float* __restrict__ h0f, float* __restrict__ h1f,
    float* __restrict__ z0f, float* __restrict__ z1f,
    unsigned long long* __restrict__ cnt, unsigned* __restrict__ info,
    unsigned long long* __restrict__ ccnt_all, char* __restrict__ cpbase) {
  __shared__ float red[256 * 33];
  __shared__ int sh_meta[5];
  const int bid = blockIdx.x;
  const int tid = threadIdx.x;
  const int myrole = (bid < 64) ? 0 : 1;

  // ---- discovery: physical XCD + ranks within XCD ----
  if (tid == 0) {
    unsigned xcc;
    asm volatile("s_getreg_b32 %0, hwreg(HW_REG_XCC_ID)" : "=s"(xcc));
    xcc &= 7u;
    llc_st32(&info[bid], 0x80000000u | xcc);
    asm volatile("s_waitcnt vmcnt(0)" ::: "memory");
    __hip_atomic_fetch_add(&cnt[4], 1ull, __ATOMIC_RELAXED, __HIP_MEMORY_SCOPE_AGENT);
    while (__hip_atomic_load(&cnt[4], __ATOMIC_RELAXED, __HIP_MEMORY_SCOPE_AGENT) < 128ull)
      __builtin_amdgcn_s_sleep(2);
    int rankA = 0, mA = 0, rankR = 0, mR = 0;
    for (int b = 0; b < 128; ++b) {
      unsigned v = (unsigned)__hip_atomic_load(&info[b], __ATOMIC_RELAXED, __HIP_MEMORY_SCOPE_AGENT);
      if ((v & 7u) == xcc) {
        int role = (b < 64) ? 0 : 1;
        if (b < bid) rankA++;
        mA++;
        if (role == myrole) { if (b < bid) rankR++; mR++; }
      }
    }
    sh_meta[0] = (int)xcc; sh_meta[1] = rankA; sh_meta[2] = mA;
    sh_meta[3] = rankR; sh_meta[4] = mR;
  }
  __syncthreads();
  const int xcd = sh_meta[0], rankA = sh_meta[1], mA = sh_meta[2];
  const int rankR = sh_meta[3], mR = sh_meta[4];
  unsigned long long* cc = ccnt_all + (size_t)xcd * 4;
  char* cpx = cpbase + (size_t)xcd * CP_XCD_STRIDE;
  _Float16* cpH0[2]  = {(_Float16*)(cpx + 0*131072), (_Float16*)(cpx + 1*131072)};
  _Float16* cpRH0[2] = {(_Float16*)(cpx + 2*131072), (_Float16*)(cpx + 3*131072)};
  _Float16* cpH1[2]  = {(_Float16*)(cpx + 4*131072), (_Float16*)(cpx + 5*131072)};
  _Float16* cpRH1[2] = {(_Float16*)(cpx + 6*131072), (_Float16*)(cpx + 7*131072)};
  const int rsub = tid & 15;

  if (myrole == 0) {
    // ---------- layer 0, step t ----------
    const int cb = bid * 32, nb = bid * 16;
    const _Float16* wpsRZ[2] = { wrz0 + (size_t)(cb + rsub) * 1536,
                                 wrz0 + (size_t)(cb + 16 + rsub) * 1536 };
    const _Float16* wpsN[1] = { wn0 + (size_t)(nb + rsub) * 1536 };
    for (int t = 0; t < 512; ++t) {
      f4 aRZ[2] = { f4{0.f,0.f,0.f,0.f}, f4{0.f,0.f,0.f,0.f} };
      f4 aN[1] = { f4{0.f,0.f,0.f,0.f} };
      gemm_x(x, t, wpsRZ[0], wpsRZ[1], wpsN[0], aRZ, aN);   // no dependency
      // phase A: rz0(t)  (needs h0(t-1); t=0 -> zeros, skip)
      wait_ge(&cnt[1], 64ull * (unsigned long long)t);
      if (t >= 1) {
        copy_tensor(h0bf + (size_t)((t - 1) & 1) * 65536, cpH0[(t - 1) & 1],
                    rankA, mA, &cc[0], (unsigned long long)mA * t);
        gemm_cp<2>(cpH0[(t - 1) & 1], wpsRZ, 512, aRZ);
      }
      red_write<2>(red, aRZ);
      __syncthreads();
      reduce_rz(red, cb, brz0, h0f, rh0, z0f);
      signal(&cnt[0]);
      // phase B: n0(t)  (needs rh0(t); t=0 -> rh0==0, skip gemm)
      wait_ge(&cnt[0], 64ull * (unsigned long long)(t + 1));
      if (t >= 1) wait_ge(&cnt[3], 64ull * (unsigned long long)(t - 1));  // h0bf WAR
      if (t >= 1) {
        copy_tensor(rh0, cpRH0[t & 1], rankR, mR, &cc[1], (unsigned long long)mR * t);
        gemm_cp<1>(cpRH0[t & 1], wpsN, 512, aN);
      }
      red_write<1>(red, aN);
      __syncthreads();
      reduce_n(red, nb, bn0, z0f, h0f, h0bf + (size_t)(t & 1) * 65536);
      signal(&cnt[1]);
    }
  } else {
    // ---------- layer 1, step s = t-1 ----------
    const int b = bid - 64, cb = b * 32, nb = b * 16;
    const _Float16* wps3[3] = { wrz1 + (size_t)(cb + rsub) * 2048,
                                wrz1 + (size_t)(cb + 16 + rsub) * 2048,
                                wn1  + (size_t)(nb + rsub) * 2048 };
    for (int t = 1; t <= 512; ++t) {
      const int s = t - 1;
      f4 acc3[3] = { f4{0.f,0.f,0.f,0.f}, f4{0.f,0.f,0.f,0.f}, f4{0.f,0.f,0.f,0.f} };
      // phase A: rz1(s): h1(s-1)-part (s=0 -> zeros, skip)
      wait_ge(&cnt[3], 64ull * (unsigned long long)s);
      if (s >= 1) {
        copy_tensor(h1bf + (size_t)((s - 1) & 1) * 65536, cpH1[(s - 1) & 1],
                    rankR, mR, &cc[2], (unsigned long long)mR * s);
        gemm_cp<2>(cpH1[(s - 1) & 1], wps3, 1024, acc3);
      }
      // h0(s)-part for rz1 AND n1 (fused NT=3, one copy)
      wait_ge(&cnt[1], 64ull * (unsigned long long)t);
      {
        int rk = (t <= 511) ? rankA : rankR;
        int mm = (t <= 511) ? mA : mR;
        unsigned long long tg = (t <= 511) ? (unsigned long long)mA * t
                                           : (unsigned long long)mA * 511 + (unsigned long long)mR;
        copy_tensor(h0bf + (size_t)((t - 1) & 1) * 65536, cpH0[(t - 1) & 1],
                    rk, mm, &cc[0], tg);
        gemm_cp<3>(cpH0[(t - 1) & 1], wps3, 0, acc3);
      }
      red_write<2>(red, acc3);
      __syncthreads();
      reduce_rz(red, cb, brz1, h1f, rh1, z1f);
      signal(&cnt[2]);
      // phase B: n1(s) rh-part (s=0 -> rh1==0, skip gemm)
      wait_ge(&cnt[2], 64ull * (unsigned long long)t);
      if (s >= 1) {
        copy_tensor(rh1, cpRH1[s & 1], rankR, mR, &cc[3], (unsigned long long)mR * s);
        gemm_cp<1>(cpRH1[s & 1], wps3 + 2, 1024, acc3 + 2);
      }
      red_write<1>(red, acc3 + 2);
      __syncthreads();
      reduce_n(red, nb, bn1, z1f, h1f, h1bf + (size_t)(s & 1) * 65536);
      signal(&cnt[3]);
    }
  }
}

// ---------------- final fc: out[64,512] = h1 @ Wfc^T + bfc ----------------
__global__ __launch_bounds__(256) void fc_kernel(const float* __restrict__ h1f,
                                                 const float* __restrict__ wfc,
                                                 const float* __restrict__ bfc,
                                                 float* __restrict__ out) {
  const int bid = blockIdx.x;  // 64 blocks x 8 cols
#pragma unroll
  for (int rep = 0; rep < 2; ++rep) {
    int local = threadIdx.x + rep * 256;
    int b = local >> 3;
    int o = bid * 8 + (local & 7);
    const float4* hp = (const float4*)(h1f + (size_t)b * 1024);
    const float4* wp = (const float4*)(wfc + (size_t)o * 1024);
    float s = 0.f;
#pragma unroll 4
    for (int i2 = 0; i2 < 256; ++i2) {
      float4 hv = hp[i2], wv = wp[i2];
      s += hv.x * wv.x + hv.y * wv.y + hv.z * wv.z + hv.w * wv.w;
    }
    out[(size_t)b * 512 + o] = s + bfc[o];
  }
}

extern "C" void kernel_launch(void* const* d_in, const int* in_sizes, int n_in,
                              void* d_out, int out_size, void* d_ws, size_t ws_size,
                              hipStream_t stream) {
  const float* x    = (const float*)d_in[0];
  const float* Wrz0 = (const float*)d_in[1];
  const float* brz0 = (const float*)d_in[2];
  const float* Wn0  = (const float*)d_in[3];
  const float* bn0  = (const float*)d_in[4];
  const float* Wrz1 = (const float*)d_in[5];
  const float* brz1 = (const float*)d_in[6];
  const float* Wn1  = (const float*)d_in[7];
  const float* bn1  = (const float*)d_in[8];
  const float* Wfc  = (const float*)d_in[9];
  const float* bfc  = (const float*)d_in[10];
  float* out = (float*)d_out;
  char* ws = (char*)d_ws;

  _Float16* wrz0h = (_Float16*)(ws + OFF_WRZ0);
  _Float16* wn0h  = (_Float16*)(ws + OFF_WN0);
  _Float16* wrz1h = (_Float16*)(ws + OFF_WRZ1);
  _Float16* wn1h  = (_Float16*)(ws + OFF_WN1);
  _Float16* h0bf  = (_Float16*)(ws + OFF_H0BF);
  _Float16* h1bf  = (_Float16*)(ws + OFF_H1BF);
  _Float16* rh0   = (_Float16*)(ws + OFF_RH0);
  _Float16* rh1   = (_Float16*)(ws + OFF_RH1);
  float* h0f = (float*)(ws + OFF_H0F);
  float* h1f = (float*)(ws + OFF_H1F);
  float* z0f = (float*)(ws + OFF_Z0F);
  float* z1f = (float*)(ws + OFF_Z1F);
  unsigned long long* cnt = (unsigned long long*)(ws + OFF_CNT);
  unsigned* info = (unsigned*)(ws + OFF_INFO);
  unsigned long long* ccnt = (unsigned long long*)(ws + OFF_CCNT);
  char* cpbase = ws + OFF_CP;

  prep_kernel<<<2048, 256, 0, stream>>>(Wrz0, Wn0, Wrz1, Wn1,
                                        wrz0h, wn0h, wrz1h, wn1h,
                                        (unsigned*)(ws + OFF_H0BF));
  gru_main<<<128, 1024, 0, stream>>>(x, wrz0h, wn0h, wrz1h, wn1h,
                                     brz0, bn0, brz1, bn1,
                                     h0bf, h1bf, rh0, rh1,
                                     h0f, h1f, z0f, z1f,
                                     cnt, info, ccnt, cpbase);
  fc_kernel<<<64, 256, 0, stream>>>(h1f, Wfc, bfc, out);
}